// Round 9
// baseline (676.830 us; speedup 1.0000x reference)
//
#include <hip/hip_runtime.h>
#include <hip/hip_bf16.h>
#include <math.h>

#define H   128
#define NR  6
#define NOUT 64

typedef __attribute__((ext_vector_type(8))) short short8;
typedef __attribute__((ext_vector_type(4))) float floatx4;

__device__ __forceinline__ float swishf(float z) {
  float t = __expf(-z);
  return z / (1.0f + t);
}

__device__ __forceinline__ ushort f2bf(float x) {
  __hip_bfloat16 b = __float2bfloat16(x);
  return *reinterpret_cast<ushort*>(&b);
}

__device__ __forceinline__ float bf2f(ushort u) {
  unsigned int v = ((unsigned int)u) << 16;
  return __uint_as_float(v);
}

// async 16B global->LDS (wave-uniform LDS base + lane*16)
__device__ __forceinline__ void async_copy16(const void* g, void* l) {
  __builtin_amdgcn_global_load_lds(
      (const __attribute__((address_space(1))) unsigned int*)g,
      (__attribute__((address_space(3))) unsigned int*)l, 16, 0, 0);
}

// ---------------- zero init (nodeA + cnt) ----------------
__global__ void k_zeroinit(float4* __restrict__ nodeA, int n4, int* __restrict__ cnt, int n) {
  int i = blockIdx.x * blockDim.x + threadIdx.x;
  if (i < n4) nodeA[i] = make_float4(0.f, 0.f, 0.f, 0.f);
  if (i < n) cnt[i] = 0;
}

// ---------------- merged weight conversion ----------------
__global__ void k_prep(const float* __restrict__ Wl, const float* __restrict__ Wx,
                       const float* __restrict__ Wls, const float* __restrict__ Wout,
                       ushort* __restrict__ Wlbf,
                       ushort* __restrict__ Wxhi, ushort* __restrict__ Wxlo,
                       ushort* __restrict__ Wlshi, ushort* __restrict__ Wlslo,
                       ushort* __restrict__ Wouthi, ushort* __restrict__ Woutlo) {
  int idx = blockIdx.x * blockDim.x + threadIdx.x;
  if (idx < 49152) {
    Wlbf[idx] = f2bf(Wl[idx]);
    return;
  }
  idx -= 49152;
  if (idx < 16384) {
    float x = Wx[idx];
    ushort h = f2bf(x);
    Wxhi[idx] = h; Wxlo[idx] = f2bf(x - bf2f(h));
    return;
  }
  idx -= 16384;
  if (idx < 49152) {
    float x = Wls[idx];
    ushort h = f2bf(x);
    Wlshi[idx] = h; Wlslo[idx] = f2bf(x - bf2f(h));
    return;
  }
  idx -= 49152;
  if (idx < 8192) {
    float x = Wout[idx];
    ushort h = f2bf(x);
    Wouthi[idx] = h; Woutlo[idx] = f2bf(x - bf2f(h));
  }
}

// ---------------- counting sort by dst: hist / scan / scatter ----------------
__global__ void k_hist(const int* __restrict__ dst, int* __restrict__ cnt, int E) {
  int i = blockIdx.x * blockDim.x + threadIdx.x;
  if (i < E) atomicAdd(&cnt[dst[i]], 1);
}

__global__ __launch_bounds__(1024) void k_scan(const int* __restrict__ cnt,
                                               int* __restrict__ cur, int N) {
  __shared__ int wsum[16];
  const int tid = threadIdx.x;
  const int chunk = (N + 1023) / 1024;
  int lo = tid * chunk, hi = min(lo + chunk, N);
  int s = 0;
  for (int i = lo; i < hi; ++i) s += cnt[i];
  const int lane = tid & 63, wv = tid >> 6;
  int v = s;
#pragma unroll
  for (int off = 1; off < 64; off <<= 1) {
    int t = __shfl_up(v, off, 64);
    if (lane >= off) v += t;
  }
  if (lane == 63) wsum[wv] = v;
  __syncthreads();
  if (wv == 0 && lane < 16) {
    int t = wsum[lane];
#pragma unroll
    for (int off = 1; off < 16; off <<= 1) {
      int u2 = __shfl_up(t, off, 64);
      if (lane >= off) t += u2;
    }
    wsum[lane] = t;  // inclusive wave sums
  }
  __syncthreads();
  int base = (wv > 0 ? wsum[wv - 1] : 0) + (v - s);
  int run = base;
  for (int i = lo; i < hi; ++i) { int c = cnt[i]; cur[i] = run; run += c; }
}

__global__ void k_scatter(const int* __restrict__ dst, int* __restrict__ cur,
                          int* __restrict__ perm, int E) {
  int i = blockIdx.x * blockDim.x + threadIdx.x;
  if (i >= E) return;
  int p = atomicAdd(&cur[dst[i]], 1);
  perm[p] = i;
}

// ---------------- triplet angles ----------------
__global__ void k_angle(const float* __restrict__ pos, const int* __restrict__ ii,
                        const int* __restrict__ jj, const int* __restrict__ kk,
                        float* __restrict__ out, int T) {
  int t = blockIdx.x * blockDim.x + threadIdx.x;
  if (t >= T) return;
  int i = ii[t], j = jj[t], k = kk[t];
  float pix = pos[i * 3], piy = pos[i * 3 + 1], piz = pos[i * 3 + 2];
  float vjx = pos[j * 3] - pix, vjy = pos[j * 3 + 1] - piy, vjz = pos[j * 3 + 2] - piz;
  float vkx = pos[k * 3] - pix, vky = pos[k * 3 + 1] - piy, vkz = pos[k * 3 + 2] - piz;
  float a = vjx * vkx + vjy * vky + vjz * vkz;
  float cx = vjy * vkz - vjz * vky;
  float cy = vjz * vkx - vjx * vkz;
  float cz = vjx * vky - vjy * vkx;
  float b = sqrtf(cx * cx + cy * cy + cz * cz);
  out[t] = atan2f(b, a);
}

// ---------------- split-precision MFMA GEMM, 64-row tiles ----------------
template <int NT, bool SWISH, bool BIAS, bool OBF>
__global__ __launch_bounds__(256) void k_gemm_split(
    const float* __restrict__ A,
    const ushort* __restrict__ Bhi,   // [NT][128]
    const ushort* __restrict__ Blo,
    const float* __restrict__ bias,
    void* __restrict__ C,
    int M) {
  constexpr int NJ = NT / 32;
  __shared__ alignas(16) ushort Ah[64 * 32];
  __shared__ alignas(16) ushort Al[64 * 32];
  __shared__ alignas(16) ushort Bh[NT * 32];
  __shared__ alignas(16) ushort Bl[NT * 32];

  const int tid = threadIdx.x;
  const int m0 = blockIdx.x * 64;
  const int w = tid >> 6, lane = tid & 63;
  const int l15 = lane & 15, quad = lane >> 4;
  const int wm = (w >> 1) * 32;
  const int wn = (w & 1) * (NT / 2);

  floatx4 acc[2][NJ];
#pragma unroll
  for (int i = 0; i < 2; ++i)
#pragma unroll
    for (int j = 0; j < NJ; ++j) acc[i][j] = floatx4{0.f, 0.f, 0.f, 0.f};

  for (int c = 0; c < 4; ++c) {
    const int kb = c * 32;
    {
      int row = tid >> 2, g = tid & 3;
      int m = m0 + row;
      float4 v0 = make_float4(0.f, 0.f, 0.f, 0.f), v1 = v0;
      if (m < M) {
        v0 = *(const float4*)&A[(size_t)m * 128 + kb + g * 8];
        v1 = *(const float4*)&A[(size_t)m * 128 + kb + g * 8 + 4];
      }
      float xs[8] = {v0.x, v0.y, v0.z, v0.w, v1.x, v1.y, v1.z, v1.w};
      short8 hi, lo;
#pragma unroll
      for (int j = 0; j < 8; ++j) {
        ushort h = f2bf(xs[j]);
        hi[j] = (short)h;
        lo[j] = (short)f2bf(xs[j] - bf2f(h));
      }
      int slot = row * 4 + (g ^ ((row >> 1) & 3));
      *(short8*)(Ah + slot * 8) = hi;
      *(short8*)(Al + slot * 8) = lo;
    }
#pragma unroll
    for (int it = 0; it < (NT * 4) / 256; ++it) {
      int ub = it * 256 + w * 64;
      int s = ub + lane;
      int brow = s >> 2, gp = s & 3;
      int gg = gp ^ ((brow >> 1) & 3);
      int lb = __builtin_amdgcn_readfirstlane(ub);
      async_copy16((const void*)(Bhi + (size_t)brow * 128 + kb + gg * 8), (void*)(Bh + lb * 8));
      async_copy16((const void*)(Blo + (size_t)brow * 128 + kb + gg * 8), (void*)(Bl + lb * 8));
    }
    __syncthreads();
    short8 ah[2], al[2], bh[NJ], blv[NJ];
#pragma unroll
    for (int i = 0; i < 2; ++i) {
      int m = wm + i * 16 + l15;
      int slot = m * 4 + (quad ^ ((m >> 1) & 3));
      ah[i] = *(const short8*)(Ah + slot * 8);
      al[i] = *(const short8*)(Al + slot * 8);
    }
#pragma unroll
    for (int j = 0; j < NJ; ++j) {
      int n = wn + j * 16 + l15;
      int slot = n * 4 + (quad ^ ((n >> 1) & 3));
      bh[j] = *(const short8*)(Bh + slot * 8);
      blv[j] = *(const short8*)(Bl + slot * 8);
    }
#pragma unroll
    for (int i = 0; i < 2; ++i)
#pragma unroll
      for (int j = 0; j < NJ; ++j) {
        acc[i][j] = __builtin_amdgcn_mfma_f32_16x16x32_bf16(ah[i], bh[j], acc[i][j], 0, 0, 0);
        acc[i][j] = __builtin_amdgcn_mfma_f32_16x16x32_bf16(ah[i], blv[j], acc[i][j], 0, 0, 0);
        acc[i][j] = __builtin_amdgcn_mfma_f32_16x16x32_bf16(al[i], bh[j], acc[i][j], 0, 0, 0);
      }
    __syncthreads();
  }

#pragma unroll
  for (int i = 0; i < 2; ++i)
#pragma unroll
    for (int r = 0; r < 4; ++r) {
      int m = m0 + wm + i * 16 + quad * 4 + r;
      if (m < M) {
#pragma unroll
        for (int j = 0; j < NJ; ++j) {
          int n = wn + j * 16 + l15;
          float z = acc[i][j][r];
          if (BIAS) z += bias[n];
          if (SWISH) z = swishf(z);
          if (OBF) ((ushort*)C)[(size_t)m * NT + n] = f2bf(z);
          else     ((float*)C)[(size_t)m * NT + n] = z;
        }
      }
    }
}

// ---------------- fused node MLP: 3x (swish o Wls) + Wout ----------------
__global__ __launch_bounds__(256, 4) void k_node_mlp(
    const float* __restrict__ nodeA,   // [M][128]
    const ushort* __restrict__ Wlshi,  // [3][128][128]
    const ushort* __restrict__ Wlslo,
    const ushort* __restrict__ Wouthi, // [64][128]
    const ushort* __restrict__ Woutlo,
    const float* __restrict__ bls,     // [3][128]
    float* __restrict__ P,             // [M][64]
    int M) {
  __shared__ alignas(16) ushort AactH[64 * 16 * 8];
  __shared__ alignas(16) ushort AactL[64 * 16 * 8];
  __shared__ alignas(16) ushort Bh[128 * 4 * 8];
  __shared__ alignas(16) ushort Bl[128 * 4 * 8];
  __shared__ float blsS[3 * 128];

  const int tid = threadIdx.x;
  const int m0 = blockIdx.x * 64;
  const int w = tid >> 6, lane = tid & 63;
  const int l15 = lane & 15, quad = lane >> 4;
  const int wm = (w >> 1) * 32;
  const int wn = (w & 1) * 64;

  for (int i = tid; i < 3 * 128; i += 256) blsS[i] = bls[i];

  floatx4 acc[2][4];

  for (int p = 0; p < 3; ++p) {
    const ushort* Bhg = Wlshi + p * 128 * 128;
    const ushort* Blg = Wlslo + p * 128 * 128;
#pragma unroll
    for (int i = 0; i < 2; ++i)
#pragma unroll
      for (int j = 0; j < 4; ++j) acc[i][j] = floatx4{0.f, 0.f, 0.f, 0.f};

    for (int c = 0; c < 4; ++c) {
      const int kb = c * 32;
#pragma unroll
      for (int it = 0; it < 2; ++it) {
        int ub = it * 256 + w * 64;
        int s = ub + lane;
        int brow = s >> 2, gp = s & 3;
        int gg = gp ^ ((brow >> 1) & 3);
        int lb = __builtin_amdgcn_readfirstlane(ub);
        async_copy16((const void*)(Bhg + (size_t)brow * 128 + kb + gg * 8), (void*)(Bh + lb * 8));
        async_copy16((const void*)(Blg + (size_t)brow * 128 + kb + gg * 8), (void*)(Bl + lb * 8));
      }
      __syncthreads();
      short8 ah[2], al[2];
      if (p == 0) {
#pragma unroll
        for (int i = 0; i < 2; ++i) {
          int m = m0 + wm + i * 16 + l15;
          float4 v0 = make_float4(0.f, 0.f, 0.f, 0.f), v1 = v0;
          if (m < M) {
            v0 = *(const float4*)&nodeA[(size_t)m * 128 + kb + quad * 8];
            v1 = *(const float4*)&nodeA[(size_t)m * 128 + kb + quad * 8 + 4];
          }
          float xs[8] = {v0.x, v0.y, v0.z, v0.w, v1.x, v1.y, v1.z, v1.w};
#pragma unroll
          for (int j = 0; j < 8; ++j) {
            ushort hh = f2bf(xs[j]);
            ah[i][j] = (short)hh;
            al[i][j] = (short)f2bf(xs[j] - bf2f(hh));
          }
        }
      } else {
#pragma unroll
        for (int i = 0; i < 2; ++i) {
          int arow = wm + i * 16 + l15;
          int g16 = c * 4 + quad;
          int slot = arow * 16 + (g16 ^ (arow & 15));
          ah[i] = *(const short8*)(AactH + slot * 8);
          al[i] = *(const short8*)(AactL + slot * 8);
        }
      }
      short8 bh[4], blv[4];
#pragma unroll
      for (int j = 0; j < 4; ++j) {
        int n = wn + j * 16 + l15;
        int slot = n * 4 + (quad ^ ((n >> 1) & 3));
        bh[j] = *(const short8*)(Bh + slot * 8);
        blv[j] = *(const short8*)(Bl + slot * 8);
      }
#pragma unroll
      for (int i = 0; i < 2; ++i)
#pragma unroll
        for (int j = 0; j < 4; ++j) {
          acc[i][j] = __builtin_amdgcn_mfma_f32_16x16x32_bf16(ah[i], bh[j], acc[i][j], 0, 0, 0);
          acc[i][j] = __builtin_amdgcn_mfma_f32_16x16x32_bf16(ah[i], blv[j], acc[i][j], 0, 0, 0);
          acc[i][j] = __builtin_amdgcn_mfma_f32_16x16x32_bf16(al[i], bh[j], acc[i][j], 0, 0, 0);
        }
      __syncthreads();
    }
#pragma unroll
    for (int i = 0; i < 2; ++i)
#pragma unroll
      for (int r = 0; r < 4; ++r) {
        int row = wm + i * 16 + quad * 4 + r;
#pragma unroll
        for (int j = 0; j < 4; ++j) {
          int col = wn + j * 16 + l15;
          float z = acc[i][j][r] + blsS[p * 128 + col];
          z = swishf(z);
          ushort hh = f2bf(z);
          int slot = row * 16 + ((col >> 3) ^ (row & 15));
          AactH[slot * 8 + (col & 7)] = hh;
          AactL[slot * 8 + (col & 7)] = f2bf(z - bf2f(hh));
        }
      }
    __syncthreads();
  }

  const int wn3 = (w & 1) * 32;
#pragma unroll
  for (int i = 0; i < 2; ++i)
#pragma unroll
    for (int j = 0; j < 2; ++j) acc[i][j] = floatx4{0.f, 0.f, 0.f, 0.f};

  for (int c = 0; c < 4; ++c) {
    const int kb = c * 32;
    {
      int ub = w * 64;
      int s = ub + lane;
      int brow = s >> 2, gp = s & 3;
      int gg = gp ^ ((brow >> 1) & 3);
      int lb = __builtin_amdgcn_readfirstlane(ub);
      async_copy16((const void*)(Wouthi + (size_t)brow * 128 + kb + gg * 8), (void*)(Bh + lb * 8));
      async_copy16((const void*)(Woutlo + (size_t)brow * 128 + kb + gg * 8), (void*)(Bl + lb * 8));
    }
    __syncthreads();
    short8 ah[2], al[2], bh[2], blv[2];
#pragma unroll
    for (int i = 0; i < 2; ++i) {
      int arow = wm + i * 16 + l15;
      int g16 = c * 4 + quad;
      int slot = arow * 16 + (g16 ^ (arow & 15));
      ah[i] = *(const short8*)(AactH + slot * 8);
      al[i] = *(const short8*)(AactL + slot * 8);
    }
#pragma unroll
    for (int j = 0; j < 2; ++j) {
      int n = wn3 + j * 16 + l15;
      int slot = n * 4 + (quad ^ ((n >> 1) & 3));
      bh[j] = *(const short8*)(Bh + slot * 8);
      blv[j] = *(const short8*)(Bl + slot * 8);
    }
#pragma unroll
    for (int i = 0; i < 2; ++i)
#pragma unroll
      for (int j = 0; j < 2; ++j) {
        acc[i][j] = __builtin_amdgcn_mfma_f32_16x16x32_bf16(ah[i], bh[j], acc[i][j], 0, 0, 0);
        acc[i][j] = __builtin_amdgcn_mfma_f32_16x16x32_bf16(ah[i], blv[j], acc[i][j], 0, 0, 0);
        acc[i][j] = __builtin_amdgcn_mfma_f32_16x16x32_bf16(al[i], bh[j], acc[i][j], 0, 0, 0);
      }
    __syncthreads();
  }
#pragma unroll
  for (int i = 0; i < 2; ++i)
#pragma unroll
    for (int r = 0; r < 4; ++r) {
      int m = m0 + wm + i * 16 + quad * 4 + r;
      if (m < M) {
#pragma unroll
        for (int j = 0; j < 2; ++j) {
          int n = wn3 + j * 16 + l15;
          P[(size_t)m * NOUT + n] = acc[i][j][r];
        }
      }
    }
}

// ---------------- MFMA fused edge block: 128-edge tile, in-kernel features ----------------
// K=384 = [h_dst | h_src | rbf_h] in 6 chunks of 64. rbf + rbf_h computed in-block
// (each sorted edge belongs to exactly one block). LDS = 40960 B -> 4 blocks/CU.
__global__ __launch_bounds__(256, 4) void k_edge_mfma(
    const ushort* __restrict__ hbf,    // [N][128] bf16
    const ushort* __restrict__ Wlbf,   // [128][384] bf16
    const float* __restrict__ bl,      // [128]
    const float* __restrict__ pos,     // [N][3]
    const float* __restrict__ freq,    // [6]
    const float* __restrict__ Wr,      // [128][6]
    const float* __restrict__ br,      // [128]
    const float* __restrict__ Wrbf,    // [128][6]
    const int* __restrict__ esrc, const int* __restrict__ edst,
    const int* __restrict__ perm,      // sorted-by-dst edge ids
    float* __restrict__ node,          // [N,128]
    int E, int nb, int perXcd) {
  __shared__ alignas(16) ushort ABs[2 * 128 * 64 + 256];  // As|Bs; epilogue alias fp32 redS[128][65]
  __shared__ float rbfS[128][6];
  __shared__ float wrS[NR][128];
  __shared__ float brS[128];
  __shared__ int dstS[128];
  __shared__ int srcS[128];

  // XCD-contiguous swizzle: sorted-dst ranges map to one XCD's L2.
  const int bp = blockIdx.x;
  const int lb = (bp & 7) * perXcd + (bp >> 3);
  if (lb >= nb) return;

  ushort* As = ABs;
  ushort* Bs = ABs + 128 * 64;

  const int tid = threadIdx.x;
  const int e0 = lb * 128;

  // ---- prologue: per-edge geometry + rbf; wrS/brS staging ----
  if (tid < 128) {
    int p = e0 + tid;
    int pc = min(p, E - 1);
    int e = perm[pc];
    int s = esrc[e], d = edst[e];
    srcS[tid] = s;
    dstS[tid] = d;
    float dx = pos[d * 3 + 0] - pos[s * 3 + 0];
    float dy = pos[d * 3 + 1] - pos[s * 3 + 1];
    float dz = pos[d * 3 + 2] - pos[s * 3 + 2];
    float dist = sqrtf(dx * dx + dy * dy + dz * dz);
    float dn = dist * 0.2f;
    float inv = 1.0f / dn;
    float dn2 = dn * dn;
    float dp = dn2 * dn2 * dn;  // dn^5
    float env = inv - 21.0f * dp + 35.0f * dp * dn - 15.0f * dp * dn2;
    bool valid = (p < E);
#pragma unroll
    for (int r = 0; r < NR; ++r)
      rbfS[tid][r] = valid ? env * sinf(freq[r] * dn) : 0.f;
  } else {
    int c = tid - 128;  // 0..127
    brS[c] = br[c];
  }
  for (int idx = tid; idx < NR * 128; idx += 256) {
    int r = idx >> 7, c = idx & 127;
    wrS[r][c] = Wr[c * NR + r];
  }
  __syncthreads();

  const int w = tid >> 6;
  const int lane = tid & 63;
  const int l15 = lane & 15, quad = lane >> 4;
  const int wm = (w >> 1) * 64;
  const int wn = (w & 1) * 64;
  const int wslot = w * 256;

  floatx4 acc[4][4];
#pragma unroll
  for (int i = 0; i < 4; ++i)
#pragma unroll
    for (int j = 0; j < 4; ++j) acc[i][j] = floatx4{0.f, 0.f, 0.f, 0.f};

  for (int c = 0; c < 6; ++c) {
    // ---- stage A tile ----
    if (c < 4) {
      const int* rowS = (c < 2) ? dstS : srcS;
      const int off = (c & 1) * 64;
#pragma unroll
      for (int i = 0; i < 4; ++i) {
        int u = wslot + i * 64 + lane;
        int nrow = u >> 3, gp = u & 7;
        int g = gp ^ (nrow & 7);
        int row = rowS[nrow];
        const ushort* gsrc = hbf + (size_t)row * H + off + g * 8;
        int lbo = __builtin_amdgcn_readfirstlane(wslot + i * 64);
        async_copy16((const void*)gsrc, (void*)(As + lbo * 8));
      }
    } else {
      // compute rbf_h = swish(rbf @ Wr^T + br) directly into swizzled As
      const int off = (c & 1) * 64;   // c=4 -> cols 0..63, c=5 -> cols 64..127
#pragma unroll
      for (int it = 0; it < 4; ++it) {
        int u = it * 256 + tid;       // 0..1023
        int m = u >> 3, g = u & 7;
        float rb[NR];
#pragma unroll
        for (int q = 0; q < NR; ++q) rb[q] = rbfS[m][q];
        short8 pk;
#pragma unroll
        for (int j = 0; j < 8; ++j) {
          int col = off + g * 8 + j;
          float z = brS[col];
#pragma unroll
          for (int q = 0; q < NR; ++q) z += rb[q] * wrS[q][col];
          pk[j] = (short)f2bf(swishf(z));
        }
        *(short8*)(As + (m * 8 + (g ^ (m & 7))) * 8) = pk;
      }
    }
    // ---- stage B tile ----
    {
#pragma unroll
      for (int i = 0; i < 4; ++i) {
        int u = wslot + i * 64 + lane;
        int nrow = u >> 3, gp = u & 7;
        int g = gp ^ (nrow & 7);
        const ushort* gsrc = Wlbf + (size_t)nrow * 384 + c * 64 + g * 8;
        int lbo = __builtin_amdgcn_readfirstlane(wslot + i * 64);
        async_copy16((const void*)gsrc, (void*)(Bs + lbo * 8));
      }
    }
    __syncthreads();
#pragma unroll
    for (int s = 0; s < 2; ++s) {
      const int gg = s * 4 + quad;
      short8 af[4], bfr[4];
#pragma unroll
      for (int i = 0; i < 4; ++i) {
        int m = wm + i * 16 + l15;
        af[i] = *(const short8*)(As + (m * 8 + (gg ^ (m & 7))) * 8);
      }
#pragma unroll
      for (int j = 0; j < 4; ++j) {
        int n = wn + j * 16 + l15;
        bfr[j] = *(const short8*)(Bs + (n * 8 + (gg ^ (n & 7))) * 8);
      }
#pragma unroll
      for (int i = 0; i < 4; ++i)
#pragma unroll
        for (int j = 0; j < 4; ++j)
          acc[i][j] = __builtin_amdgcn_mfma_f32_16x16x32_bf16(af[i], bfr[j], acc[i][j], 0, 0, 0);
    }
    __syncthreads();
  }

  // ---- epilogue: t = swish(z+bl) * (rbf . Wrbf[n]); segmented sum over sorted dst ----
  float* redS = (float*)ABs;   // [128][65]
  float wt[4][NR], blv[4];
#pragma unroll
  for (int j = 0; j < 4; ++j) {
    int n = wn + j * 16 + l15;
    blv[j] = bl[n];
#pragma unroll
    for (int r = 0; r < NR; ++r) wt[j][r] = Wrbf[n * NR + r];
  }

  for (int half = 0; half < 2; ++half) {
    __syncthreads();
    if ((w & 1) == half) {
#pragma unroll
      for (int i = 0; i < 4; ++i)
#pragma unroll
        for (int r = 0; r < 4; ++r) {
          int m = wm + i * 16 + quad * 4 + r;
          float rb[NR];
#pragma unroll
          for (int q = 0; q < NR; ++q) rb[q] = rbfS[m][q];
#pragma unroll
          for (int j = 0; j < 4; ++j) {
            float z = acc[i][j][r] + blv[j];
            float ev = swishf(z);
            float wv = 0.f;
#pragma unroll
            for (int q = 0; q < NR; ++q) wv += rb[q] * wt[j][q];
            redS[m * 65 + j * 16 + l15] = ev * wv;   // zero when p>=E (rb==0)
          }
        }
    }
    __syncthreads();
    int cc = tid & 63, chunk = tid >> 6;
    int mstart = chunk * 32;
    float s = 0.f;
    int prev = dstS[mstart];
    for (int m = mstart; m < mstart + 32; ++m) {
      int d = dstS[m];
      float v = redS[m * 65 + cc];
      if (d != prev) {
        atomicAdd(&node[(size_t)prev * H + half * 64 + cc], s);
        s = 0.f;
        prev = d;
      }
      s += v;
    }
    atomicAdd(&node[(size_t)prev * H + half * 64 + cc], s);
  }
}

extern "C" void kernel_launch(void* const* d_in, const int* in_sizes, int n_in,
                              void* d_out, int out_size, void* d_ws, size_t ws_size,
                              hipStream_t stream) {
  const float* x    = (const float*)d_in[0];
  const float* pos  = (const float*)d_in[1];
  const float* freq = (const float*)d_in[2];
  const float* Wx   = (const float*)d_in[3];
  const float* Wr   = (const float*)d_in[4];
  const float* br   = (const float*)d_in[5];
  const float* Wl   = (const float*)d_in[6];
  const float* bl   = (const float*)d_in[7];
  const float* Wrbf = (const float*)d_in[8];
  const float* Wls  = (const float*)d_in[9];
  const float* bls  = (const float*)d_in[10];
  const float* Wout = (const float*)d_in[11];
  const int* esrc = (const int*)d_in[12];
  const int* edst = (const int*)d_in[13];
  const int* ii   = (const int*)d_in[14];
  const int* jjv  = (const int*)d_in[15];
  const int* kkv  = (const int*)d_in[16];

  const int N = in_sizes[0] / H;
  const int E = in_sizes[12];
  const int T = in_sizes[14];

  float* out   = (float*)d_out;
  float* P     = out;                       // [N,64]
  float* angle = out + (size_t)N * NOUT;    // [T]

  float* ws = (float*)d_ws;
  float* nodeA = ws; ws += (size_t)N * H;
  ushort* u = (ushort*)ws;
  ushort* hbf    = u; u += (size_t)N * H;
  ushort* Wlbf   = u; u += 3 * H * H;
  ushort* Wxhi   = u; u += H * H;
  ushort* Wxlo   = u; u += H * H;
  ushort* Wlshi  = u; u += 3 * H * H;
  ushort* Wlslo  = u; u += 3 * H * H;
  ushort* Wouthi = u; u += NOUT * H;
  ushort* Woutlo = u; u += NOUT * H;
  int* ip = (int*)u;
  int* cnt   = ip; ip += N;
  int* cur   = ip; ip += N;
  int* perm  = ip; ip += E;

  // zeros (nodeA + cnt)
  {
    int n4 = N * H / 4;
    k_zeroinit<<<(n4 + 255) / 256, 256, 0, stream>>>((float4*)nodeA, n4, cnt, N);
  }

  // counting sort of edges by dst
  k_hist<<<(E + 255) / 256, 256, 0, stream>>>(edst, cnt, E);
  k_scan<<<1, 1024, 0, stream>>>(cnt, cur, N);
  k_scatter<<<(E + 255) / 256, 256, 0, stream>>>(edst, cur, perm, E);

  // merged weight converts/splits
  k_prep<<<(122880 + 255) / 256, 256, 0, stream>>>(Wl, Wx, Wls, Wout, Wlbf,
                                                   Wxhi, Wxlo, Wlshi, Wlslo, Wouthi, Woutlo);

  // angles
  if (T > 0)
    k_angle<<<(T + 255) / 256, 256, 0, stream>>>(pos, ii, jjv, kkv, angle, T);

  // h = x @ Wx^T -> bf16
  k_gemm_split<128, false, false, true><<<(N + 63) / 64, 256, 0, stream>>>(
      x, Wxhi, Wxlo, nullptr, hbf, N);

  // fused MFMA edge block (features in-kernel) -> segmented sum into nodeA
  {
    int nb = (E + 127) / 128;
    int perXcd = (nb + 7) / 8;
    int grid = perXcd * 8;
    k_edge_mfma<<<grid, 256, 0, stream>>>(hbf, Wlbf, bl, pos, freq, Wr, br, Wrbf,
                                          esrc, edst, perm, nodeA, E, nb, perXcd);
  }

  // fused node MLP
  k_node_mlp<<<(N + 63) / 64, 256, 0, stream>>>(nodeA, Wlshi, Wlslo, Wouthi, Woutlo,
                                                bls, P, N);
}